// Round 3
// baseline (529.528 us; speedup 1.0000x reference)
//
#include <hip/hip_runtime.h>

// Problem constants
#define B_    256
#define A_    100
#define NB_   10
#define BOND_ 110
#define AF_   82
#define BF_   6
#define H_    300
#define NP_   320           // padded H
#define MA_   (B_ * A_)     // 25600
#define MB_   (B_ * BOND_)  // 28160
#define KP300 320
#define KP82  96

typedef __attribute__((ext_vector_type(8))) short short8;
typedef __attribute__((ext_vector_type(4))) float f32x4;

// ---- bf16 helpers (RNE via bit trick) ----
__device__ __forceinline__ ushort f2bf(float v) {
    union { float f; unsigned u; } x; x.f = v;
    unsigned r = x.u + 0x7fffu + ((x.u >> 16) & 1u);
    return (ushort)(r >> 16);
}
__device__ __forceinline__ float bf2f(ushort h) {
    union { float f; unsigned u; } x; x.u = ((unsigned)h) << 16;
    return x.f;
}

// ---- async global->LDS, 16B per lane ----
__device__ __forceinline__ void gload16(const void* g, void* l) {
    __builtin_amdgcn_global_load_lds(
        (const __attribute__((address_space(1))) void*)g,
        (__attribute__((address_space(3))) void*)l, 16, 0, 0);
}

// ===========================================================================
// MFMA GEMM, split-bf16 (3-term), B direct-from-global (pre-fragmented):
//   C[100 rows/block, 320] = epi( A@W (+ A2@W2) )
// Grid: 256 blocks (1/CU), 256 threads = 4 waves; wave w owns cols [80w,80w+80)
// (ct=5 16-col tiles); rows: rt=7 16-row tiles (112 staged, 100 written).
// A: [M][KP] bf16 hi/lo row-major, staged to LDS (pitch 80B, 2-way-free banks),
//    TRIPLE-buffered, counted-vmcnt pipeline (T3/T4-minimum).
// W: pre-fragmented frag[ks][ct(20)][lane(64)][8 bf16] so one dwordx4/lane = 1 frag.
// OUTMODE: 0=split bf16 hi/lo [M][320], 1=f32 [M][320], 2=final (*E, rowmask, [M][300])
// ===========================================================================
template<bool DUAL, bool BIAS, bool RELU, int OUTMODE>
__global__ __launch_bounds__(256, 1) void mgemm_k(
    const ushort* __restrict__ aH, const ushort* __restrict__ aL,
    const ushort* __restrict__ fH, const ushort* __restrict__ fL,
    const ushort* __restrict__ aH2, const ushort* __restrict__ aL2,
    const ushort* __restrict__ fH2, const ushort* __restrict__ fL2,
    int KP,
    const float* __restrict__ bias,
    const float* __restrict__ E,
    const int*   __restrict__ n_atoms,
    ushort* __restrict__ oHi, ushort* __restrict__ oLo,
    float*  __restrict__ oF)
{
    __shared__ char lds[3 * 20480];       // 3 buffers: 128 rows x 80B x {hi,lo}
    const int tid  = threadIdx.x;
    const int lane = tid & 63;
    const int l16  = lane & 15;
    const int kg   = lane >> 4;
    const int w    = tid >> 6;
    const int rowbase = blockIdx.x * 100;

    const int nks   = KP >> 5;
    const int total = (DUAL ? 2 : 1) * nks;

    // Precompute per-q staging decode (q = 0..4; granule g = q*256 + tid)
    int st_row[5], st_choff[5], st_plane[5];
    #pragma unroll
    for (int q = 0; q < 5; ++q) {
        int g = q * 256 + tid;
        int plane = (g >= 640) ? 1 : 0;
        int local = g - plane * 640;
        int row = local / 5;
        int ch  = local % 5; if (ch == 4) ch = 3;   // dead pad granule
        int grow = rowbase + row; if (grow >= MA_) grow = MA_ - 1;
        st_row[q] = grow; st_choff[q] = ch * 16; st_plane[q] = plane;
    }

    auto stage = [&](int t) {
        int pass = (DUAL && t >= nks) ? 1 : 0;
        int ks   = t - (pass ? nks : 0);
        const ushort* SH = pass ? aH2 : aH;
        const ushort* SL = pass ? aL2 : aL;
        char* dst = (char*)lds + (t % 3) * 20480 + (tid & 192) * 16;
        #pragma unroll
        for (int q = 0; q < 5; ++q) {
            const ushort* src = (st_plane[q] ? SL : SH) + (size_t)st_row[q] * KP + ks * 32;
            gload16((const char*)src + st_choff[q], dst + q * 4096);
        }
    };

    f32x4 acc[7][5] = {};

    stage(0);
    for (int tk = 0; tk < total; ++tk) {
        // B fragments for this k-step -> registers (L2-resident, coalesced 1KB/instr)
        short8 bh[5], bl[5];
        {
            int pass = (DUAL && tk >= nks) ? 1 : 0;
            int ks   = tk - (pass ? nks : 0);
            const ushort* FHp = pass ? fH2 : fH;
            const ushort* FLp = pass ? fL2 : fL;
            size_t base = ((size_t)ks * 20 + w * 5) * 512 + (size_t)lane * 8;
            #pragma unroll
            for (int c = 0; c < 5; ++c) {
                bh[c] = *(const short8*)(FHp + base + c * 512);
                bl[c] = *(const short8*)(FLp + base + c * 512);
            }
        }
        // prefetch next A tile (flies under this k-step's MFMAs)
        if (tk + 1 < total) stage(tk + 1);

        // wait: A(tk) + B(tk) done; the 5 newest (A(tk+1) staging) stay in flight
        if (tk + 1 < total) { asm volatile("s_waitcnt vmcnt(5)" ::: "memory"); }
        else                { asm volatile("s_waitcnt vmcnt(0)" ::: "memory"); }
        __builtin_amdgcn_s_barrier();
        __builtin_amdgcn_sched_barrier(0);

        const char* ab = (const char*)lds + (tk % 3) * 20480;
        const int ao = l16 * 80 + kg * 16;
        #pragma unroll
        for (int rt = 0; rt < 7; ++rt) {
            short8 ah = *(const short8*)(ab + rt * 1280 + ao);
            short8 al = *(const short8*)(ab + 10240 + rt * 1280 + ao);
            #pragma unroll
            for (int c = 0; c < 5; ++c) {
                acc[rt][c] = __builtin_amdgcn_mfma_f32_16x16x32_bf16(ah, bh[c], acc[rt][c], 0, 0, 0);
                acc[rt][c] = __builtin_amdgcn_mfma_f32_16x16x32_bf16(al, bh[c], acc[rt][c], 0, 0, 0);
                acc[rt][c] = __builtin_amdgcn_mfma_f32_16x16x32_bf16(ah, bl[c], acc[rt][c], 0, 0, 0);
            }
        }
        __builtin_amdgcn_s_barrier();   // compute done before next buf rotation overwrite
    }

    // epilogue  (C/D map: col = l16 (+16c+80w), row = rt*16 + kg*4 + r)
    float biasv[5];
    #pragma unroll
    for (int c = 0; c < 5; ++c) {
        int col = w * 80 + c * 16 + l16;
        biasv[c] = (BIAS && col < H_) ? bias[col] : 0.f;
    }
    #pragma unroll
    for (int rt = 0; rt < 7; ++rt) {
        #pragma unroll
        for (int c = 0; c < 5; ++c) {
            const int col = w * 80 + c * 16 + l16;
            #pragma unroll
            for (int r = 0; r < 4; ++r) {
                const int lrow = rt * 16 + kg * 4 + r;
                if (lrow >= 100) continue;
                const int row = rowbase + lrow;
                float v = acc[rt][c][r];
                if (BIAS) v += biasv[c];
                if (RELU) v = fmaxf(v, 0.f);
                if (OUTMODE == 0) {
                    ushort hi = f2bf(v);
                    ushort lo = f2bf(v - bf2f(hi));
                    size_t o = (size_t)row * NP_ + col;
                    oHi[o] = hi; oLo[o] = lo;
                } else if (OUTMODE == 1) {
                    oF[(size_t)row * NP_ + col] = v;
                } else {
                    if (col < H_) {
                        v *= E[(size_t)row * NP_ + col];
                        int b = row / A_;
                        int a = row - b * A_;
                        if (a >= n_atoms[b]) v = 0.f;
                        oF[(size_t)row * H_ + col] = v;
                    }
                }
            }
        }
    }
}

// ---------------------------------------------------------------------------
// Weight pre-fragmentation: src [K][300] f32 ->
//   frag[ks][ct=0..19][lane=0..63][j=0..7] bf16 hi/lo, where
//   value = W[ks*32 + (lane>>4)*8 + j][ct*16 + (lane&15)]  (0 outside K/300)
// ---------------------------------------------------------------------------
__global__ __launch_bounds__(256) void conv_wfrag_k(
    const float* __restrict__ src, int K, int KP,
    ushort* __restrict__ dH, ushort* __restrict__ dL)
{
    int idx = blockIdx.x * 256 + threadIdx.x;
    int nwords = (KP >> 5) * 20 * 64;
    if (idx >= nwords) return;
    int lane = idx & 63;
    int t  = idx >> 6;
    int ct = t % 20;
    int ks = t / 20;
    int col = ct * 16 + (lane & 15);
    int k0  = ks * 32 + (lane >> 4) * 8;
    short8 hv, lv;
    #pragma unroll
    for (int j = 0; j < 8; ++j) {
        int k = k0 + j;
        float v = (col < H_ && k < K) ? src[(size_t)k * H_ + col] : 0.f;
        ushort h = f2bf(v);
        hv[j] = (short)h;
        lv[j] = (short)f2bf(v - bf2f(h));
    }
    *(short8*)(dH + (size_t)idx * 8) = hv;
    *(short8*)(dL + (size_t)idx * 8) = lv;
}

// atom_feats [M][82] f32 -> [M][96] bf16 hi/lo (zero-padded)
__global__ __launch_bounds__(256) void conv_af_k(
    const float* __restrict__ src, ushort* __restrict__ dhi, ushort* __restrict__ dlo)
{
    int idx = blockIdx.x * 256 + threadIdx.x;
    if (idx >= MA_ * KP82) return;
    int row = idx / KP82, k = idx - row * KP82;
    float v = (k < AF_) ? src[(size_t)row * AF_ + k] : 0.f;
    ushort hi = f2bf(v);
    dhi[idx] = hi;
    dlo[idx] = f2bf(v - bf2f(hi));
}

// ---------------------------------------------------------------------------
// Bond K=6 matvec: out[MB][320] = bond[MB][6] @ w[6][300] (+bias), pad cols = 0
// ---------------------------------------------------------------------------
__global__ __launch_bounds__(256) void bondmm_k(
    const float* __restrict__ bf, const float* __restrict__ wmat,
    const float* __restrict__ bias, float* __restrict__ out)
{
    int idx = blockIdx.x * 256 + threadIdx.x;
    if (idx >= MB_ * 80) return;
    int row = idx / 80, c4 = idx - row * 80;
    float4 s = make_float4(0.f, 0.f, 0.f, 0.f);
    if (c4 < 75) {
        int col = c4 * 4;
        if (bias) s = *(const float4*)(bias + col);
        #pragma unroll
        for (int k = 0; k < 6; ++k) {
            float b = bf[(size_t)row * 6 + k];
            float4 wv = *(const float4*)(wmat + (size_t)k * H_ + col);
            s.x = fmaf(b, wv.x, s.x); s.y = fmaf(b, wv.y, s.y);
            s.z = fmaf(b, wv.z, s.z); s.w = fmaf(b, wv.w, s.w);
        }
    }
    *(float4*)(out + (size_t)row * NP_ + c4 * 4) = s;
}

// ---------------------------------------------------------------------------
// nei[ba,:] = sum_{n<nn} relu(hw[arow] + bwn[brow])   -> split bf16 out
// ---------------------------------------------------------------------------
__global__ __launch_bounds__(256) void agg_relu_k(
    const float* __restrict__ hw, const float* __restrict__ bwn,
    const int* __restrict__ ag, const int* __restrict__ bg,
    const int* __restrict__ num_nbs,
    ushort* __restrict__ neiH, ushort* __restrict__ neiL)
{
    int idx = blockIdx.x * 256 + threadIdx.x;
    if (idx >= MA_ * 80) return;
    int ba = idx / 80, c4 = idx - ba * 80;
    int nn = num_nbs[ba];
    const int* agp = ag + (size_t)ba * NB_ * 2;
    const int* bgp = bg + (size_t)ba * NB_ * 2;
    float4 s = make_float4(0.f, 0.f, 0.f, 0.f);
    for (int n = 0; n < nn; ++n) {
        int arow = agp[2*n] * A_    + agp[2*n+1];
        int brow = bgp[2*n] * BOND_ + bgp[2*n+1];
        float4 hv = *(const float4*)(hw  + (size_t)arow * NP_ + c4 * 4);
        float4 bv = *(const float4*)(bwn + (size_t)brow * NP_ + c4 * 4);
        s.x += fmaxf(hv.x + bv.x, 0.f); s.y += fmaxf(hv.y + bv.y, 0.f);
        s.z += fmaxf(hv.z + bv.z, 0.f); s.w += fmaxf(hv.w + bv.w, 0.f);
    }
    size_t o = (size_t)ba * NP_ + c4 * 4;
    ushort4 hi, lo;
    hi.x = f2bf(s.x); lo.x = f2bf(s.x - bf2f(hi.x));
    hi.y = f2bf(s.y); lo.y = f2bf(s.y - bf2f(hi.y));
    hi.z = f2bf(s.z); lo.z = f2bf(s.z - bf2f(hi.z));
    hi.w = f2bf(s.w); lo.w = f2bf(s.w - bf2f(hi.w));
    *(ushort4*)(neiH + o) = hi;
    *(ushort4*)(neiL + o) = lo;
}

// nei[ba,:] = sum_{n<nn} hw2[arow] * bw2[brow]   -> f32 out
__global__ __launch_bounds__(256) void agg_prod_k(
    const float* __restrict__ hw2, const float* __restrict__ bw2,
    const int* __restrict__ ag, const int* __restrict__ bg,
    const int* __restrict__ num_nbs, float* __restrict__ neiF)
{
    int idx = blockIdx.x * 256 + threadIdx.x;
    if (idx >= MA_ * 80) return;
    int ba = idx / 80, c4 = idx - ba * 80;
    int nn = num_nbs[ba];
    const int* agp = ag + (size_t)ba * NB_ * 2;
    const int* bgp = bg + (size_t)ba * NB_ * 2;
    float4 s = make_float4(0.f, 0.f, 0.f, 0.f);
    for (int n = 0; n < nn; ++n) {
        int arow = agp[2*n] * A_    + agp[2*n+1];
        int brow = bgp[2*n] * BOND_ + bgp[2*n+1];
        float4 hv = *(const float4*)(hw2 + (size_t)arow * NP_ + c4 * 4);
        float4 bv = *(const float4*)(bw2 + (size_t)brow * NP_ + c4 * 4);
        s.x = fmaf(hv.x, bv.x, s.x); s.y = fmaf(hv.y, bv.y, s.y);
        s.z = fmaf(hv.z, bv.z, s.z); s.w = fmaf(hv.w, bv.w, s.w);
    }
    *(float4*)(neiF + (size_t)ba * NP_ + c4 * 4) = s;
}

// ===========================================================================
extern "C" void kernel_launch(void* const* d_in, const int* in_sizes, int n_in,
                              void* d_out, int out_size, void* d_ws, size_t ws_size,
                              hipStream_t stream)
{
    const float* atom_feats = (const float*)d_in[0];
    const float* bond_feats = (const float*)d_in[1];
    const float* w_fc1      = (const float*)d_in[2];
    const float* w_nei      = (const float*)d_in[3];
    const float* b_nei      = (const float*)d_in[4];
    const float* w_atom     = (const float*)d_in[5];
    const float* b_atom     = (const float*)d_in[6];
    const float* w2a        = (const float*)d_in[7];
    const float* w2b        = (const float*)d_in[8];
    const float* w_fc2      = (const float*)d_in[9];
    const int*   atom_graph = (const int*)d_in[10];
    const int*   bond_graph = (const int*)d_in[11];
    const int*   num_nbs    = (const int*)d_in[12];
    const int*   n_atoms    = (const int*)d_in[13];
    float* out = (float*)d_out;
    (void)in_sizes; (void)n_in; (void)out_size; (void)ws_size;

    // workspace layout (identical element counts to round-2 layout)
    const size_t SZ_H16 = (size_t)MA_ * NP_ * 2;
    const size_t SZ_HF  = (size_t)MA_ * NP_ * 4;
    const size_t SZ_BWN = (size_t)MB_ * NP_ * 4;
    const size_t SZ_AF  = (size_t)MA_ * KP82 * 2;
    const size_t SZ_WT  = (size_t)NP_ * KP300 * 2;
    const size_t SZ_WT1 = (size_t)NP_ * KP82 * 2;
    char* p = (char*)d_ws;
    ushort* hA_h = (ushort*)p; p += SZ_H16;
    ushort* hA_l = (ushort*)p; p += SZ_H16;
    ushort* hB_h = (ushort*)p; p += SZ_H16;
    ushort* hB_l = (ushort*)p; p += SZ_H16;
    ushort* nei_h = (ushort*)p; p += SZ_H16;
    ushort* nei_l = (ushort*)p; p += SZ_H16;
    float* hwF = (float*)p; p += SZ_HF;
    float* bwn = (float*)p; p += SZ_BWN;
    ushort* af_h = (ushort*)p; p += SZ_AF;
    ushort* af_l = (ushort*)p; p += SZ_AF;
    ushort* wfc1_h = (ushort*)p; p += SZ_WT1;
    ushort* wfc1_l = (ushort*)p; p += SZ_WT1;
    ushort* wn1_h  = (ushort*)p; p += SZ_WT;
    ushort* wn1_l  = (ushort*)p; p += SZ_WT;
    ushort* wa1_h  = (ushort*)p; p += SZ_WT;
    ushort* wa1_l  = (ushort*)p; p += SZ_WT;
    ushort* wa2_h  = (ushort*)p; p += SZ_WT;
    ushort* wa2_l  = (ushort*)p; p += SZ_WT;
    ushort* w2a_h  = (ushort*)p; p += SZ_WT;
    ushort* w2a_l  = (ushort*)p; p += SZ_WT;
    ushort* wfc2_h = (ushort*)p; p += SZ_WT;
    ushort* wfc2_l = (ushort*)p; p += SZ_WT;
    float* neiF = (float*)hB_h;   // alias: hB pair dead before agg_prod

    const dim3 blk(256);
    const dim3 gG(256);                          // 1 block per CU
    const int  aggG  = (MA_ * 80 + 255) / 256;
    const int  bondG = (MB_ * 80 + 255) / 256;
    const int  fw300 = ((KP300 >> 5) * 20 * 64 + 255) / 256;  // 50
    const int  fw96  = ((KP82  >> 5) * 20 * 64 + 255) / 256;  // 15

    // conversions
    conv_af_k<<<(MA_*KP82+255)/256, blk, 0, stream>>>(atom_feats, af_h, af_l);
    conv_wfrag_k<<<fw96,  blk, 0, stream>>>(w_fc1, AF_, KP82, wfc1_h, wfc1_l);
    conv_wfrag_k<<<fw300, blk, 0, stream>>>(w_nei,                 H_, KP300, wn1_h, wn1_l);
    conv_wfrag_k<<<fw300, blk, 0, stream>>>(w_atom,                H_, KP300, wa1_h, wa1_l);
    conv_wfrag_k<<<fw300, blk, 0, stream>>>(w_atom + (size_t)H_*H_, H_, KP300, wa2_h, wa2_l);
    conv_wfrag_k<<<fw300, blk, 0, stream>>>(w2a,                   H_, KP300, w2a_h, w2a_l);
    conv_wfrag_k<<<fw300, blk, 0, stream>>>(w_fc2,                 H_, KP300, wfc2_h, wfc2_l);

    // bwn = bond_feats @ w_nei[300:,:] + b_nei
    bondmm_k<<<bondG, blk, 0, stream>>>(bond_feats, w_nei + (size_t)H_*H_, b_nei, bwn);

    // h = relu(af @ w_fc1)
    mgemm_k<false,false,true,0><<<gG, blk, 0, stream>>>(
        af_h, af_l, wfc1_h, wfc1_l, nullptr,nullptr,nullptr,nullptr, KP82,
        nullptr, nullptr, nullptr, hA_h, hA_l, nullptr);

    ushort* hc_h = hA_h; ushort* hc_l = hA_l;
    ushort* hn_h = hB_h; ushort* hn_l = hB_l;
    for (int it = 0; it < 2; ++it) {
        mgemm_k<false,false,false,1><<<gG, blk, 0, stream>>>(
            hc_h, hc_l, wn1_h, wn1_l, nullptr,nullptr,nullptr,nullptr, KP300,
            nullptr, nullptr, nullptr, nullptr, nullptr, hwF);
        agg_relu_k<<<aggG, blk, 0, stream>>>(hwF, bwn, atom_graph, bond_graph, num_nbs, nei_h, nei_l);
        mgemm_k<true,true,true,0><<<gG, blk, 0, stream>>>(
            hc_h, hc_l, wa1_h, wa1_l, nei_h, nei_l, wa2_h, wa2_l, KP300,
            b_atom, nullptr, nullptr, hn_h, hn_l, nullptr);
        ushort* t;
        t = hc_h; hc_h = hn_h; hn_h = t;
        t = hc_l; hc_l = hn_l; hn_l = t;
    }
    // hc = hA pair; hB pair dead -> neiF alias safe

    bondmm_k<<<bondG, blk, 0, stream>>>(bond_feats, w2b, nullptr, bwn);
    mgemm_k<false,false,false,1><<<gG, blk, 0, stream>>>(
        hc_h, hc_l, w2a_h, w2a_l, nullptr,nullptr,nullptr,nullptr, KP300,
        nullptr, nullptr, nullptr, nullptr, nullptr, hwF);
    agg_prod_k<<<aggG, blk, 0, stream>>>(hwF, bwn, atom_graph, bond_graph, num_nbs, neiF);
    mgemm_k<false,false,false,2><<<gG, blk, 0, stream>>>(
        hc_h, hc_l, wfc2_h, wfc2_l, nullptr,nullptr,nullptr,nullptr, KP300,
        nullptr, neiF, n_atoms, nullptr, nullptr, out);
}

// Round 4
// 454.483 us; speedup vs baseline: 1.1651x; 1.1651x over previous
//
#include <hip/hip_runtime.h>

// Problem constants
#define B_    256
#define A_    100
#define NB_   10
#define BOND_ 110
#define AF_   82
#define BF_   6
#define H_    300
#define NP_   320           // padded H
#define MA_   (B_ * A_)     // 25600
#define MB_   (B_ * BOND_)  // 28160
#define KP300 320
#define KP82  96

typedef __attribute__((ext_vector_type(8))) short short8;
typedef __attribute__((ext_vector_type(4))) float f32x4;

// ---- bf16 helpers (RNE via bit trick) ----
__device__ __forceinline__ ushort f2bf(float v) {
    union { float f; unsigned u; } x; x.f = v;
    unsigned r = x.u + 0x7fffu + ((x.u >> 16) & 1u);
    return (ushort)(r >> 16);
}
__device__ __forceinline__ float bf2f(ushort h) {
    union { float f; unsigned u; } x; x.u = ((unsigned)h) << 16;
    return x.f;
}

// ---- async global->LDS, 16B per lane ----
__device__ __forceinline__ void gload16(const void* g, void* l) {
    __builtin_amdgcn_global_load_lds(
        (const __attribute__((address_space(1))) void*)g,
        (__attribute__((address_space(3))) void*)l, 16, 0, 0);
}

// ===========================================================================
// MFMA GEMM, split-bf16 (3-term), B direct-from-global (pre-fragmented):
//   C[64 rows/block, 320] = epi( A@W (+ A2@W2) )
// Grid: 400 blocks (2 blocks/CU on most CUs -> 2 waves/SIMD latency hiding).
// 256 threads = 4 waves; wave w owns cols [80w, 80w+80) = ct 5 x 16-col tiles;
// rows: rt 4 x 16-row tiles (64 = BM exactly, M=25600=400*64, no masking).
// A: [M][KP] bf16 hi/lo row-major, staged to LDS with 64B row pitch
//    (bank-slot spread (16*l16+4*kg)%32 covers all 8 slots evenly -> optimal),
//    TRIPLE-buffered, exactly 2 gload16/thread/k-step -> uniform vmcnt(2),
//    single barrier per k-step (triple buffer makes 2nd barrier redundant).
// W: pre-fragmented frag[ks][ct(20)][lane(64)][8 bf16]: one dwordx4 = 1 frag.
// OUTMODE: 0=split bf16 hi/lo [M][320], 1=f32 [M][320], 2=final (*E, rowmask, [M][300])
// ===========================================================================
template<bool DUAL, bool BIAS, bool RELU, int OUTMODE>
__global__ __launch_bounds__(256, 2) void mgemm_k(
    const ushort* __restrict__ aH, const ushort* __restrict__ aL,
    const ushort* __restrict__ fH, const ushort* __restrict__ fL,
    const ushort* __restrict__ aH2, const ushort* __restrict__ aL2,
    const ushort* __restrict__ fH2, const ushort* __restrict__ fL2,
    int KP,
    const float* __restrict__ bias,
    const float* __restrict__ E,
    const int*   __restrict__ n_atoms,
    ushort* __restrict__ oHi, ushort* __restrict__ oLo,
    float*  __restrict__ oF)
{
    __shared__ char lds[3 * 8192];        // 3 buffers: [2 planes][64 rows][64 B]
    const int tid  = threadIdx.x;
    const int lane = tid & 63;
    const int l16  = lane & 15;
    const int kg   = lane >> 4;
    const int w    = tid >> 6;
    const int rowbase = blockIdx.x * 64;

    const int nks   = KP >> 5;
    const int total = (DUAL ? 2 : 1) * nks;

    // staging decode: thread stages granule (row=tid>>2, ch=tid&3) of hi and lo
    const size_t srow = (size_t)(rowbase + (tid >> 2)) * KP; // ushort offset of row
    const int    sch  = (tid & 3) * 8;                       // ushort offset in row

    auto stage = [&](int t) {
        int pass = (DUAL && t >= nks) ? 1 : 0;
        int ks   = t - (pass ? nks : 0);
        const ushort* SH = pass ? aH2 : aH;
        const ushort* SL = pass ? aL2 : aL;
        char* dst = (char*)lds + (t % 3) * 8192 + (tid & 192) * 16;
        gload16(SH + srow + ks * 32 + sch, dst);           // hi plane
        gload16(SL + srow + ks * 32 + sch, dst + 4096);    // lo plane
    };

    f32x4 acc[4][5] = {};
    const int aoff = l16 * 64 + kg * 16;

    stage(0);
    for (int tk = 0; tk < total; ++tk) {
        // B fragments for this k-step -> registers (L2-resident, 1KB/instr)
        short8 bh[5], bl[5];
        {
            int pass = (DUAL && tk >= nks) ? 1 : 0;
            int ks   = tk - (pass ? nks : 0);
            const ushort* FHp = pass ? fH2 : fH;
            const ushort* FLp = pass ? fL2 : fL;
            size_t base = ((size_t)ks * 20 + w * 5) * 512 + (size_t)lane * 8;
            #pragma unroll
            for (int c = 0; c < 5; ++c) {
                bh[c] = *(const short8*)(FHp + base + c * 512);
                bl[c] = *(const short8*)(FLp + base + c * 512);
            }
        }
        // prefetch next A tile (2 gload16/thread, flies under MFMAs)
        if (tk + 1 < total) stage(tk + 1);

        // A(tk) + B(tk) complete; the 2 newest (stage tk+1) stay in flight
        if (tk + 1 < total) { asm volatile("s_waitcnt vmcnt(2)" ::: "memory"); }
        else                { asm volatile("s_waitcnt vmcnt(0)" ::: "memory"); }
        __builtin_amdgcn_s_barrier();
        __builtin_amdgcn_sched_barrier(0);

        const char* ab = (const char*)lds + (tk % 3) * 8192;
        #pragma unroll
        for (int rt = 0; rt < 4; ++rt) {
            short8 ah = *(const short8*)(ab +        rt * 1024 + aoff);
            short8 al = *(const short8*)(ab + 4096 + rt * 1024 + aoff);
            #pragma unroll
            for (int c = 0; c < 5; ++c) {
                acc[rt][c] = __builtin_amdgcn_mfma_f32_16x16x32_bf16(ah, bh[c], acc[rt][c], 0, 0, 0);
                acc[rt][c] = __builtin_amdgcn_mfma_f32_16x16x32_bf16(al, bh[c], acc[rt][c], 0, 0, 0);
                acc[rt][c] = __builtin_amdgcn_mfma_f32_16x16x32_bf16(ah, bl[c], acc[rt][c], 0, 0, 0);
            }
        }
        // no 2nd barrier: triple buffer => next overwrite of this buf is 3 steps
        // away and globally ordered behind the next barrier.
    }

    // epilogue  (C/D map: col = l16 (+16c+80w), row = rt*16 + kg*4 + r)
    float biasv[5];
    #pragma unroll
    for (int c = 0; c < 5; ++c) {
        int col = w * 80 + c * 16 + l16;
        biasv[c] = (BIAS && col < H_) ? bias[col] : 0.f;
    }
    #pragma unroll
    for (int rt = 0; rt < 4; ++rt) {
        #pragma unroll
        for (int c = 0; c < 5; ++c) {
            const int col = w * 80 + c * 16 + l16;
            #pragma unroll
            for (int r = 0; r < 4; ++r) {
                const int row = rowbase + rt * 16 + kg * 4 + r;
                float v = acc[rt][c][r];
                if (BIAS) v += biasv[c];
                if (RELU) v = fmaxf(v, 0.f);
                if (OUTMODE == 0) {
                    ushort hi = f2bf(v);
                    ushort lo = f2bf(v - bf2f(hi));
                    size_t o = (size_t)row * NP_ + col;
                    oHi[o] = hi; oLo[o] = lo;
                } else if (OUTMODE == 1) {
                    oF[(size_t)row * NP_ + col] = v;
                } else {
                    if (col < H_) {
                        v *= E[(size_t)row * NP_ + col];
                        int b = row / A_;
                        int a = row - b * A_;
                        if (a >= n_atoms[b]) v = 0.f;
                        oF[(size_t)row * H_ + col] = v;
                    }
                }
            }
        }
    }
}

// ---------------------------------------------------------------------------
// Weight pre-fragmentation: src [K][300] f32 ->
//   frag[ks][ct=0..19][lane=0..63][j=0..7] bf16 hi/lo, where
//   value = W[ks*32 + (lane>>4)*8 + j][ct*16 + (lane&15)]  (0 outside K/300)
// ---------------------------------------------------------------------------
__global__ __launch_bounds__(256) void conv_wfrag_k(
    const float* __restrict__ src, int K, int KP,
    ushort* __restrict__ dH, ushort* __restrict__ dL)
{
    int idx = blockIdx.x * 256 + threadIdx.x;
    int nwords = (KP >> 5) * 20 * 64;
    if (idx >= nwords) return;
    int lane = idx & 63;
    int t  = idx >> 6;
    int ct = t % 20;
    int ks = t / 20;
    int col = ct * 16 + (lane & 15);
    int k0  = ks * 32 + (lane >> 4) * 8;
    short8 hv, lv;
    #pragma unroll
    for (int j = 0; j < 8; ++j) {
        int k = k0 + j;
        float v = (col < H_ && k < K) ? src[(size_t)k * H_ + col] : 0.f;
        ushort h = f2bf(v);
        hv[j] = (short)h;
        lv[j] = (short)f2bf(v - bf2f(h));
    }
    *(short8*)(dH + (size_t)idx * 8) = hv;
    *(short8*)(dL + (size_t)idx * 8) = lv;
}

// atom_feats [M][82] f32 -> [M][96] bf16 hi/lo (zero-padded)
__global__ __launch_bounds__(256) void conv_af_k(
    const float* __restrict__ src, ushort* __restrict__ dhi, ushort* __restrict__ dlo)
{
    int idx = blockIdx.x * 256 + threadIdx.x;
    if (idx >= MA_ * KP82) return;
    int row = idx / KP82, k = idx - row * KP82;
    float v = (k < AF_) ? src[(size_t)row * AF_ + k] : 0.f;
    ushort hi = f2bf(v);
    dhi[idx] = hi;
    dlo[idx] = f2bf(v - bf2f(hi));
}

// ---------------------------------------------------------------------------
// Bond K=6 matvec: out[MB][320] = bond[MB][6] @ w[6][300] (+bias), pad cols = 0
// ---------------------------------------------------------------------------
__global__ __launch_bounds__(256) void bondmm_k(
    const float* __restrict__ bf, const float* __restrict__ wmat,
    const float* __restrict__ bias, float* __restrict__ out)
{
    int idx = blockIdx.x * 256 + threadIdx.x;
    if (idx >= MB_ * 80) return;
    int row = idx / 80, c4 = idx - row * 80;
    float4 s = make_float4(0.f, 0.f, 0.f, 0.f);
    if (c4 < 75) {
        int col = c4 * 4;
        if (bias) s = *(const float4*)(bias + col);
        #pragma unroll
        for (int k = 0; k < 6; ++k) {
            float b = bf[(size_t)row * 6 + k];
            float4 wv = *(const float4*)(wmat + (size_t)k * H_ + col);
            s.x = fmaf(b, wv.x, s.x); s.y = fmaf(b, wv.y, s.y);
            s.z = fmaf(b, wv.z, s.z); s.w = fmaf(b, wv.w, s.w);
        }
    }
    *(float4*)(out + (size_t)row * NP_ + c4 * 4) = s;
}

// ---------------------------------------------------------------------------
// nei[ba,:] = sum_{n<nn} relu(hw[arow] + bwn[brow])   -> split bf16 out
// ---------------------------------------------------------------------------
__global__ __launch_bounds__(256) void agg_relu_k(
    const float* __restrict__ hw, const float* __restrict__ bwn,
    const int* __restrict__ ag, const int* __restrict__ bg,
    const int* __restrict__ num_nbs,
    ushort* __restrict__ neiH, ushort* __restrict__ neiL)
{
    int idx = blockIdx.x * 256 + threadIdx.x;
    if (idx >= MA_ * 80) return;
    int ba = idx / 80, c4 = idx - ba * 80;
    int nn = num_nbs[ba];
    const int* agp = ag + (size_t)ba * NB_ * 2;
    const int* bgp = bg + (size_t)ba * NB_ * 2;
    float4 s = make_float4(0.f, 0.f, 0.f, 0.f);
    for (int n = 0; n < nn; ++n) {
        int arow = agp[2*n] * A_    + agp[2*n+1];
        int brow = bgp[2*n] * BOND_ + bgp[2*n+1];
        float4 hv = *(const float4*)(hw  + (size_t)arow * NP_ + c4 * 4);
        float4 bv = *(const float4*)(bwn + (size_t)brow * NP_ + c4 * 4);
        s.x += fmaxf(hv.x + bv.x, 0.f); s.y += fmaxf(hv.y + bv.y, 0.f);
        s.z += fmaxf(hv.z + bv.z, 0.f); s.w += fmaxf(hv.w + bv.w, 0.f);
    }
    size_t o = (size_t)ba * NP_ + c4 * 4;
    ushort4 hi, lo;
    hi.x = f2bf(s.x); lo.x = f2bf(s.x - bf2f(hi.x));
    hi.y = f2bf(s.y); lo.y = f2bf(s.y - bf2f(hi.y));
    hi.z = f2bf(s.z); lo.z = f2bf(s.z - bf2f(hi.z));
    hi.w = f2bf(s.w); lo.w = f2bf(s.w - bf2f(hi.w));
    *(ushort4*)(neiH + o) = hi;
    *(ushort4*)(neiL + o) = lo;
}

// nei[ba,:] = sum_{n<nn} hw2[arow] * bw2[brow]   -> f32 out
__global__ __launch_bounds__(256) void agg_prod_k(
    const float* __restrict__ hw2, const float* __restrict__ bw2,
    const int* __restrict__ ag, const int* __restrict__ bg,
    const int* __restrict__ num_nbs, float* __restrict__ neiF)
{
    int idx = blockIdx.x * 256 + threadIdx.x;
    if (idx >= MA_ * 80) return;
    int ba = idx / 80, c4 = idx - ba * 80;
    int nn = num_nbs[ba];
    const int* agp = ag + (size_t)ba * NB_ * 2;
    const int* bgp = bg + (size_t)ba * NB_ * 2;
    float4 s = make_float4(0.f, 0.f, 0.f, 0.f);
    for (int n = 0; n < nn; ++n) {
        int arow = agp[2*n] * A_    + agp[2*n+1];
        int brow = bgp[2*n] * BOND_ + bgp[2*n+1];
        float4 hv = *(const float4*)(hw2 + (size_t)arow * NP_ + c4 * 4);
        float4 bv = *(const float4*)(bw2 + (size_t)brow * NP_ + c4 * 4);
        s.x = fmaf(hv.x, bv.x, s.x); s.y = fmaf(hv.y, bv.y, s.y);
        s.z = fmaf(hv.z, bv.z, s.z); s.w = fmaf(hv.w, bv.w, s.w);
    }
    *(float4*)(neiF + (size_t)ba * NP_ + c4 * 4) = s;
}

// ===========================================================================
extern "C" void kernel_launch(void* const* d_in, const int* in_sizes, int n_in,
                              void* d_out, int out_size, void* d_ws, size_t ws_size,
                              hipStream_t stream)
{
    const float* atom_feats = (const float*)d_in[0];
    const float* bond_feats = (const float*)d_in[1];
    const float* w_fc1      = (const float*)d_in[2];
    const float* w_nei      = (const float*)d_in[3];
    const float* b_nei      = (const float*)d_in[4];
    const float* w_atom     = (const float*)d_in[5];
    const float* b_atom     = (const float*)d_in[6];
    const float* w2a        = (const float*)d_in[7];
    const float* w2b        = (const float*)d_in[8];
    const float* w_fc2      = (const float*)d_in[9];
    const int*   atom_graph = (const int*)d_in[10];
    const int*   bond_graph = (const int*)d_in[11];
    const int*   num_nbs    = (const int*)d_in[12];
    const int*   n_atoms    = (const int*)d_in[13];
    float* out = (float*)d_out;
    (void)in_sizes; (void)n_in; (void)out_size; (void)ws_size;

    // workspace layout
    const size_t SZ_H16 = (size_t)MA_ * NP_ * 2;
    const size_t SZ_HF  = (size_t)MA_ * NP_ * 4;
    const size_t SZ_BWN = (size_t)MB_ * NP_ * 4;
    const size_t SZ_AF  = (size_t)MA_ * KP82 * 2;
    const size_t SZ_WT  = (size_t)NP_ * KP300 * 2;
    const size_t SZ_WT1 = (size_t)NP_ * KP82 * 2;
    char* p = (char*)d_ws;
    ushort* hA_h = (ushort*)p; p += SZ_H16;
    ushort* hA_l = (ushort*)p; p += SZ_H16;
    ushort* hB_h = (ushort*)p; p += SZ_H16;
    ushort* hB_l = (ushort*)p; p += SZ_H16;
    ushort* nei_h = (ushort*)p; p += SZ_H16;
    ushort* nei_l = (ushort*)p; p += SZ_H16;
    float* hwF = (float*)p; p += SZ_HF;
    float* bwn = (float*)p; p += SZ_BWN;
    ushort* af_h = (ushort*)p; p += SZ_AF;
    ushort* af_l = (ushort*)p; p += SZ_AF;
    ushort* wfc1_h = (ushort*)p; p += SZ_WT1;
    ushort* wfc1_l = (ushort*)p; p += SZ_WT1;
    ushort* wn1_h  = (ushort*)p; p += SZ_WT;
    ushort* wn1_l  = (ushort*)p; p += SZ_WT;
    ushort* wa1_h  = (ushort*)p; p += SZ_WT;
    ushort* wa1_l  = (ushort*)p; p += SZ_WT;
    ushort* wa2_h  = (ushort*)p; p += SZ_WT;
    ushort* wa2_l  = (ushort*)p; p += SZ_WT;
    ushort* w2a_h  = (ushort*)p; p += SZ_WT;
    ushort* w2a_l  = (ushort*)p; p += SZ_WT;
    ushort* wfc2_h = (ushort*)p; p += SZ_WT;
    ushort* wfc2_l = (ushort*)p; p += SZ_WT;
    float* neiF = (float*)hB_h;   // alias: hB pair dead before agg_prod

    const dim3 blk(256);
    const dim3 gG(MA_ / 64);                     // 400 blocks -> 2 blocks/CU
    const int  aggG  = (MA_ * 80 + 255) / 256;
    const int  bondG = (MB_ * 80 + 255) / 256;
    const int  fw300 = ((KP300 >> 5) * 20 * 64 + 255) / 256;  // 50
    const int  fw96  = ((KP82  >> 5) * 20 * 64 + 255) / 256;  // 15

    // conversions
    conv_af_k<<<(MA_*KP82+255)/256, blk, 0, stream>>>(atom_feats, af_h, af_l);
    conv_wfrag_k<<<fw96,  blk, 0, stream>>>(w_fc1, AF_, KP82, wfc1_h, wfc1_l);
    conv_wfrag_k<<<fw300, blk, 0, stream>>>(w_nei,                 H_, KP300, wn1_h, wn1_l);
    conv_wfrag_k<<<fw300, blk, 0, stream>>>(w_atom,                H_, KP300, wa1_h, wa1_l);
    conv_wfrag_k<<<fw300, blk, 0, stream>>>(w_atom + (size_t)H_*H_, H_, KP300, wa2_h, wa2_l);
    conv_wfrag_k<<<fw300, blk, 0, stream>>>(w2a,                   H_, KP300, w2a_h, w2a_l);
    conv_wfrag_k<<<fw300, blk, 0, stream>>>(w_fc2,                 H_, KP300, wfc2_h, wfc2_l);

    // bwn = bond_feats @ w_nei[300:,:] + b_nei
    bondmm_k<<<bondG, blk, 0, stream>>>(bond_feats, w_nei + (size_t)H_*H_, b_nei, bwn);

    // h = relu(af @ w_fc1)
    mgemm_k<false,false,true,0><<<gG, blk, 0, stream>>>(
        af_h, af_l, wfc1_h, wfc1_l, nullptr,nullptr,nullptr,nullptr, KP82,
        nullptr, nullptr, nullptr, hA_h, hA_l, nullptr);

    ushort* hc_h = hA_h; ushort* hc_l = hA_l;
    ushort* hn_h = hB_h; ushort* hn_l = hB_l;
    for (int it = 0; it < 2; ++it) {
        mgemm_k<false,false,false,1><<<gG, blk, 0, stream>>>(
            hc_h, hc_l, wn1_h, wn1_l, nullptr,nullptr,nullptr,nullptr, KP300,
            nullptr, nullptr, nullptr, nullptr, nullptr, hwF);
        agg_relu_k<<<aggG, blk, 0, stream>>>(hwF, bwn, atom_graph, bond_graph, num_nbs, nei_h, nei_l);
        mgemm_k<true,true,true,0><<<gG, blk, 0, stream>>>(
            hc_h, hc_l, wa1_h, wa1_l, nei_h, nei_l, wa2_h, wa2_l, KP300,
            b_atom, nullptr, nullptr, hn_h, hn_l, nullptr);
        ushort* t;
        t = hc_h; hc_h = hn_h; hn_h = t;
        t = hc_l; hc_l = hn_l; hn_l = t;
    }
    // hc = hA pair; hB pair dead -> neiF alias safe

    bondmm_k<<<bondG, blk, 0, stream>>>(bond_feats, w2b, nullptr, bwn);
    mgemm_k<false,false,false,1><<<gG, blk, 0, stream>>>(
        hc_h, hc_l, w2a_h, w2a_l, nullptr,nullptr,nullptr,nullptr, KP300,
        nullptr, nullptr, nullptr, nullptr, nullptr, hwF);
    agg_prod_k<<<aggG, blk, 0, stream>>>(hwF, bwn, atom_graph, bond_graph, num_nbs, neiF);
    mgemm_k<false,false,false,2><<<gG, blk, 0, stream>>>(
        hc_h, hc_l, wfc2_h, wfc2_l, nullptr,nullptr,nullptr,nullptr, KP300,
        nullptr, neiF, n_atoms, nullptr, nullptr, out);
}